// Round 9
// baseline (43.289 us; speedup 1.0000x reference)
//
#include <hip/hip_runtime.h>

#define B_ROWS 32768
#define C_COLS 1000
#define NF4 250                 // C_COLS / 4
#define MAIN_BLOCKS 8192        // 4 waves/block, exactly 1 row per wave
#define HIST_BLOCKS 16

// --- histogram: per-block LDS counts, sparse global fp32 atomic flush
//     (round-2 proven plumbing, byte-identical) ---
__global__ __launch_bounds__(256) void bsl_hist(const int* __restrict__ target,
                                                float* __restrict__ freq) {
    __shared__ unsigned int lh[C_COLS];
    const int tid = threadIdx.x;
    for (int i = tid; i < C_COLS; i += 256) lh[i] = 0u;
    __syncthreads();
    const int4* t4 = reinterpret_cast<const int4*>(target + blockIdx.x * 2048);
    #pragma unroll
    for (int k = 0; k < 2; ++k) {
        int4 v = t4[tid + k * 256];
        atomicAdd(&lh[v.x], 1u);
        atomicAdd(&lh[v.y], 1u);
        atomicAdd(&lh[v.z], 1u);
        atomicAdd(&lh[v.w], 1u);
    }
    __syncthreads();
    for (int i = tid; i < C_COLS; i += 256) {
        unsigned int c = lh[i];
        if (c) atomicAdd(&freq[i], (float)c);
    }
}

// --- main: ONE row per wave, 4 contiguous rows per block (linear sweep of
//     pred across the grid). No row loop, no unroll tricks — max TLP. ---
__global__ __launch_bounds__(256) void bsl_main(const float* __restrict__ pred,
                                                const int* __restrict__ target,
                                                const float* __restrict__ freq,
                                                float* __restrict__ partials) {
    __shared__ float sfreq[C_COLS];
    __shared__ float swave[4];
    const int tid = threadIdx.x;
    const int lane = tid & 63;
    const int wib = tid >> 6;

    for (int i = tid; i < C_COLS; i += 256) sfreq[i] = freq[i];
    __syncthreads();
    const float4* sf4 = reinterpret_cast<const float4*>(sfreq);

    const int row = blockIdx.x * 4 + wib;       // contiguous rows per block
    const int t = target[row];
    const float4* prow = reinterpret_cast<const float4*>(pred + (size_t)row * C_COLS);
    const int t4i = t >> 2, tm = t & 3;

    float partial = 0.0f, pt = 0.0f;
    #pragma unroll
    for (int k = 0; k < 4; ++k) {
        const int j = k * 64 + lane;
        if (j < NF4) {
            const float4 v = prow[j];
            const float4 f = sf4[j];
            partial += __expf(v.x) * f.x + __expf(v.y) * f.y
                     + __expf(v.z) * f.z + __expf(v.w) * f.w;
            if (j == t4i)
                pt = (tm & 1) ? ((tm & 2) ? v.w : v.y)
                              : ((tm & 2) ? v.z : v.x);
        }
    }
    #pragma unroll
    for (int off = 32; off > 0; off >>= 1)
        partial += __shfl_xor(partial, off, 64);
    const float ptb = __shfl(pt, t4i & 63, 64);
    const float local = logf(partial) - ptb - logf(sfreq[t]);

    // `local` is wave-uniform; block-reduce the 4 wave values
    if (lane == 0) swave[wib] = local;
    __syncthreads();
    if (tid == 0)
        partials[blockIdx.x] = swave[0] + swave[1] + swave[2] + swave[3];
}

__global__ __launch_bounds__(256) void bsl_finalize(const float* __restrict__ partials,
                                                    float* __restrict__ out) {
    const int tid = threadIdx.x;
    float s = 0.0f;
    for (int i = tid; i < MAIN_BLOCKS; i += 256) s += partials[i];
    #pragma unroll
    for (int off = 32; off > 0; off >>= 1) s += __shfl_xor(s, off, 64);
    __shared__ float sw[4];
    if ((tid & 63) == 0) sw[tid >> 6] = s;
    __syncthreads();
    if (tid == 0) out[0] = (sw[0] + sw[1] + sw[2] + sw[3]) / (float)B_ROWS;
}

extern "C" void kernel_launch(void* const* d_in, const int* in_sizes, int n_in,
                              void* d_out, int out_size, void* d_ws, size_t ws_size,
                              hipStream_t stream) {
    const float* pred = (const float*)d_in[0];
    const int* target = (const int*)d_in[1];

    float* freq     = (float*)d_ws;          // [1024] histogram
    float* partials = freq + 1024;           // [MAIN_BLOCKS]

    // freq must start at zero every call (hist accumulates into it)
    hipMemsetAsync(freq, 0, 1024 * sizeof(float), stream);

    bsl_hist<<<HIST_BLOCKS, 256, 0, stream>>>(target, freq);
    bsl_main<<<MAIN_BLOCKS, 256, 0, stream>>>(pred, target, freq, partials);
    bsl_finalize<<<1, 256, 0, stream>>>(partials, (float*)d_out);
}

// Round 10
// 38.432 us; speedup vs baseline: 1.1264x; 1.1264x over previous
//
#include <hip/hip_runtime.h>

#define B_ROWS 32768
#define C_COLS 1000
#define NF4 250                 // C_COLS / 4
#define MAIN_BLOCKS 2048
#define WAVES_TOTAL (MAIN_BLOCKS * 4)
#define HIST_BLOCKS 16

// --- histogram: per-block LDS counts, sparse global fp32 atomic flush
//     (round-2 proven, byte-identical) ---
__global__ __launch_bounds__(256) void bsl_hist(const int* __restrict__ target,
                                                float* __restrict__ freq) {
    __shared__ unsigned int lh[C_COLS];
    const int tid = threadIdx.x;
    for (int i = tid; i < C_COLS; i += 256) lh[i] = 0u;
    __syncthreads();
    const int4* t4 = reinterpret_cast<const int4*>(target + blockIdx.x * 2048);
    #pragma unroll
    for (int k = 0; k < 2; ++k) {
        int4 v = t4[tid + k * 256];
        atomicAdd(&lh[v.x], 1u);
        atomicAdd(&lh[v.y], 1u);
        atomicAdd(&lh[v.z], 1u);
        atomicAdd(&lh[v.w], 1u);
    }
    __syncthreads();
    for (int i = tid; i < C_COLS; i += 256) {
        unsigned int c = lh[i];
        if (c) atomicAdd(&freq[i], (float)c);
    }
}

// --- main: round-2 proven body; ONLY change: the -log(freq[t]) term is
//     dropped here (moved to finalize as sum_c f*log f). ---
__global__ __launch_bounds__(256) void bsl_main(const float* __restrict__ pred,
                                                const int* __restrict__ target,
                                                const float* __restrict__ freq,
                                                float* __restrict__ partials) {
    __shared__ float sfreq[C_COLS];
    __shared__ float swave[4];
    const int tid = threadIdx.x;
    const int lane = tid & 63;
    const int wib = tid >> 6;

    for (int i = tid; i < C_COLS; i += 256) sfreq[i] = freq[i];
    __syncthreads();
    const float4* sf4 = reinterpret_cast<const float4*>(sfreq);

    const int gwid = blockIdx.x * 4 + wib;
    float local = 0.0f;

    for (int row = gwid; row < B_ROWS; row += WAVES_TOTAL) {
        const int t = target[row];
        const float4* prow = reinterpret_cast<const float4*>(pred + (size_t)row * C_COLS);
        const int t4i = t >> 2, tm = t & 3;
        float partial = 0.0f, pt = 0.0f;
        #pragma unroll
        for (int k = 0; k < 4; ++k) {
            const int j = k * 64 + lane;
            if (j < NF4) {
                const float4 v = prow[j];
                const float4 f = sf4[j];
                partial += __expf(v.x) * f.x + __expf(v.y) * f.y
                         + __expf(v.z) * f.z + __expf(v.w) * f.w;
                if (j == t4i)
                    pt = (tm & 1) ? ((tm & 2) ? v.w : v.y)
                                  : ((tm & 2) ? v.z : v.x);
            }
        }
        #pragma unroll
        for (int off = 32; off > 0; off >>= 1)
            partial += __shfl_xor(partial, off, 64);
        const float ptb = __shfl(pt, t4i & 63, 64);
        local += logf(partial) - ptb;
    }

    if (lane == 0) swave[wib] = local;
    __syncthreads();
    if (tid == 0)
        partials[blockIdx.x] = swave[0] + swave[1] + swave[2] + swave[3];
}

// --- finalize: sum partials, subtract sum_c freq_c * log(freq_c)
//     (== sum_b log freq[target_b]), divide by B ---
__global__ __launch_bounds__(256) void bsl_finalize(const float* __restrict__ partials,
                                                    const float* __restrict__ freq,
                                                    float* __restrict__ out) {
    const int tid = threadIdx.x;
    float s = 0.0f;
    for (int i = tid; i < MAIN_BLOCKS; i += 256) s += partials[i];
    float fl = 0.0f;
    for (int i = tid; i < C_COLS; i += 256) {
        const float f = freq[i];
        if (f > 0.0f) fl += f * logf(f);
    }
    float comb = s - fl;
    #pragma unroll
    for (int off = 32; off > 0; off >>= 1) comb += __shfl_xor(comb, off, 64);
    __shared__ float sw[4];
    if ((tid & 63) == 0) sw[tid >> 6] = comb;
    __syncthreads();
    if (tid == 0) out[0] = (sw[0] + sw[1] + sw[2] + sw[3]) / (float)B_ROWS;
}

extern "C" void kernel_launch(void* const* d_in, const int* in_sizes, int n_in,
                              void* d_out, int out_size, void* d_ws, size_t ws_size,
                              hipStream_t stream) {
    const float* pred = (const float*)d_in[0];
    const int* target = (const int*)d_in[1];

    float* freq     = (float*)d_ws;          // [1024] histogram
    float* partials = freq + 1024;           // [MAIN_BLOCKS]

    // freq must start at zero every call (hist accumulates into it)
    hipMemsetAsync(freq, 0, 1024 * sizeof(float), stream);

    bsl_hist<<<HIST_BLOCKS, 256, 0, stream>>>(target, freq);
    bsl_main<<<MAIN_BLOCKS, 256, 0, stream>>>(pred, target, freq, partials);
    bsl_finalize<<<1, 256, 0, stream>>>(partials, freq, (float*)d_out);
}